// Round 8
// baseline (455.006 us; speedup 1.0000x reference)
//
#include <hip/hip_runtime.h>

// VarianceLoss via one-hot MFMA segment reduction.  B=8, C=4, H=W=1024, NSEG=65.
//
// R7 = ABLATION ROUND.  MODE0 is the unchanged R6 kernel (real output).
// MODE1/2/3 are keepalive-stubbed variants dispatched to dead scratch, each
// with a REPS multiplier so they rank above the harness's 78us poison-fills
// in rocprof top-5:
//   MODE1: everything except the MFMA instruction (afrag/bfrag kept alive)
//   MODE2: loads + softmax + LDS staging (kt loop removed; post-loop LDS
//          readback keeps the staging stores alive)
//   MODE3: loads + softmax only (P/QQ/seg kept alive)
// Rule #17: every stubbed consumer is replaced by asm volatile "v" keepalives.

typedef unsigned short u16x2 __attribute__((ext_vector_type(2)));
typedef unsigned int   u32x4 __attribute__((ext_vector_type(4)));
typedef short          s16x8 __attribute__((ext_vector_type(8)));   // 8 x bf16
typedef float          f32x4 __attribute__((ext_vector_type(4)));

constexpr int   B_    = 8;
constexpr int   SEGS  = 64;      // segments 1..64 (segment 0 masked out by ref)
constexpr int   VALS  = 5;       // p0,p1,p2,qq,cnt
constexpr float EPS_  = 1e-8f;

constexpr int PLANE   = 528;               // bytes per plane (512 + bank skew)
constexpr int NSLOT   = 9;                 // hi0,lo0,hi1,lo1,hi2,lo2,hi3,lo3,seg
constexpr int WLDS    = NSLOT * PLANE;     // 4752 B per wave
constexpr int LDS_SZ  = (4 * WLDS > 16384) ? 4 * WLDS : 16384;   // 19008

__device__ __forceinline__ unsigned asu(float f)  { return __float_as_uint(f); }
__device__ __forceinline__ float    asf(unsigned u){ return __uint_as_float(u); }

#define KEEP1(x)  asm volatile("" :: "v"(x))
#define KEEPV(u)  asm volatile("" :: "v"((u)[0]), "v"((u)[1]), "v"((u)[2]), "v"((u)[3]))

template<int MODE, int REPS>
__global__ __launch_bounds__(256, 4) void vl_accum(const float* __restrict__ logit,
                                                   const int*   __restrict__ inst,
                                                   float* __restrict__ accOut,
                                                   int N, int ppb)
{
    __shared__ __align__(16) unsigned char lds[LDS_SZ];

    const int tid  = threadIdx.x;
    const int wid  = tid >> 6;
    const int lane = tid & 63;
    const int col  = lane & 15;
    const int quad = lane >> 4;
    const int wbase = wid * WLDS;

    const bool selLds = (col < 4) | (col >= 8 && col < 12);
    const unsigned cword = (col == 4) ? 0x3F803F80u : 0u;   // cnt hi = 1.0
    const int pl = (col < 4) ? (2 * col)
                 : ((col >= 8 && col < 12) ? (2 * (col - 8) + 1) : 0);
    const int bRd   = wbase + pl * PLANE + quad * 16;   // + kt*64
    const int segRd = wbase + 8 * PLANE + quad * 16;    // + kt*64
    const int segWr = wbase + 8 * PLANE + lane * 8;

    u16x2 rowdup[4];
#pragma unroll
    for (int t = 0; t < 4; ++t) {
        unsigned short rw = (unsigned short)(t * 16 + col);
        rowdup[t] = (u16x2){rw, rw};
    }
    const u16x2 one2  = (u16x2){1, 1};
    const u16x2 negb  = (u16x2){0xC080, 0xC080};   // -0x3F80 mod 2^16
    const u16x2 posb  = (u16x2){0x3F80, 0x3F80};

    const int b = blockIdx.y;
    const float* __restrict__ l0 = logit + (size_t)b * 4 * N;
    const int*   __restrict__ ib = inst  + (size_t)b * N;

    f32x4 acc0 = {0.f,0.f,0.f,0.f}, acc1 = {0.f,0.f,0.f,0.f};
    f32x4 acc2 = {0.f,0.f,0.f,0.f}, acc3 = {0.f,0.f,0.f,0.f};

    const int blockStart = blockIdx.x * ppb;
    const int rounds = ppb >> 10;
    const int base0  = blockStart + (wid << 8) + (lane << 2);

#define LOAD_ROUND(R, X0, X1, X2, X3, SG)                                       \
    {                                                                           \
        const int q  = base0 + ((R) << 10);                                     \
        const bool ok = (q + 4 <= N);                                           \
        const int qc = ok ? q : 0;                                              \
        X0 = *(const float4*)(l0 + qc);                                         \
        X1 = *(const float4*)(l0 + (size_t)N     + qc);                         \
        X2 = *(const float4*)(l0 + (size_t)2 * N + qc);                         \
        X3 = *(const float4*)(l0 + (size_t)3 * N + qc);                         \
        int4 sgt = *(const int4*)(ib + qc);                                     \
        SG = ok ? sgt : make_int4(0, 0, 0, 0);                                  \
    }

    for (int rep = 0; rep < REPS; ++rep) {
        float4 cx0, cx1, cx2, cx3; int4 csg;
        if (rounds > 0) LOAD_ROUND(0, cx0, cx1, cx2, cx3, csg)

        for (int r = 0; r < rounds; ++r) {
            float4 nx0, nx1, nx2, nx3; int4 nsg;
            if (r + 1 < rounds) LOAD_ROUND(r + 1, nx0, nx1, nx2, nx3, nsg)

            const float c0[4] = {cx0.x, cx0.y, cx0.z, cx0.w};
            const float c1[4] = {cx1.x, cx1.y, cx1.z, cx1.w};
            const float c2[4] = {cx2.x, cx2.y, cx2.z, cx2.w};
            const float c3[4] = {cx3.x, cx3.y, cx3.z, cx3.w};

            float P0[4], P1[4], P2[4], QQ[4];
#pragma unroll
            for (int i = 0; i < 4; ++i) {
                float va = c0[i], vb = c1[i], vc = c2[i], vd = c3[i];
                float m  = fmaxf(fmaxf(va, vb), fmaxf(vc, vd));
                float e0 = __expf(va - m);
                float e1 = __expf(vb - m);
                float e2 = __expf(vc - m);
                float e3 = __expf(vd - m);
                float rr = 1.0f / (e0 + e1 + e2 + e3);
                float q0 = e0 * rr, q1 = e1 * rr, q2 = e2 * rr, q3 = e3 * rr;
                P0[i] = q0; P1[i] = q1; P2[i] = q2;
                QQ[i] = q0*q0 + q1*q1 + q2*q2 + q3*q3;
            }

            if constexpr (MODE == 3) {
                // loads + softmax only
#pragma unroll
                for (int i = 0; i < 4; ++i) {
                    asm volatile("" :: "v"(P0[i]), "v"(P1[i]), "v"(P2[i]), "v"(QQ[i]));
                }
                asm volatile("" :: "v"(csg.x), "v"(csg.y), "v"(csg.z), "v"(csg.w));
            } else {
#define STAGE_PLANE(P, ARR)                                                     \
            {                                                                   \
                unsigned a0 = asu(ARR[0]), a1 = asu(ARR[1]);                    \
                unsigned a2 = asu(ARR[2]), a3 = asu(ARR[3]);                    \
                unsigned h1m = a1 & 0xFFFF0000u, h3m = a3 & 0xFFFF0000u;        \
                unsigned hi01 = (a0 >> 16) | h1m;                               \
                unsigned hi23 = (a2 >> 16) | h3m;                               \
                float l0f = ARR[0] - asf(a0 & 0xFFFF0000u);                     \
                float l1f = ARR[1] - asf(h1m);                                  \
                float l2f = ARR[2] - asf(a2 & 0xFFFF0000u);                     \
                float l3f = ARR[3] - asf(h3m);                                  \
                unsigned lo01 = (asu(l0f) >> 16) | (asu(l1f) & 0xFFFF0000u);    \
                unsigned lo23 = (asu(l2f) >> 16) | (asu(l3f) & 0xFFFF0000u);    \
                *(uint2*)(lds + wbase + (2*(P)) * PLANE + lane * 8)   = make_uint2(hi01, hi23); \
                *(uint2*)(lds + wbase + (2*(P)+1) * PLANE + lane * 8) = make_uint2(lo01, lo23); \
            }
                STAGE_PLANE(0, P0)
                STAGE_PLANE(1, P1)
                STAGE_PLANE(2, P2)
                STAGE_PLANE(3, QQ)
#undef STAGE_PLANE
                {
                    unsigned r0 = (unsigned)(csg.x - 1) & 0xFFFFu;
                    unsigned r1 = (unsigned)(csg.y - 1) & 0xFFFFu;
                    unsigned r2 = (unsigned)(csg.z - 1) & 0xFFFFu;
                    unsigned r3 = (unsigned)(csg.w - 1) & 0xFFFFu;
                    *(uint2*)(lds + segWr) = make_uint2(r0 | (r1 << 16), r2 | (r3 << 16));
                }

                if constexpr (MODE != 2) {
#pragma unroll
                    for (int kt = 0; kt < 8; ++kt) {
                        s16x8 braw = *(const s16x8*)(lds + bRd   + kt * 64);
                        u32x4 sv   = *(const u32x4*)(lds + segRd + kt * 64);
                        u32x4 bw   = __builtin_bit_cast(u32x4, braw);
#pragma unroll
                        for (int i = 0; i < 4; ++i) bw[i] = selLds ? bw[i] : cword;
                        s16x8 bfrag = __builtin_bit_cast(s16x8, bw);
                        if constexpr (MODE == 1) { KEEPV(bw); }

#define DO_TILE(T, ACC)                                                         \
                        {                                                       \
                            u32x4 fr;                                           \
                            _Pragma("unroll")                                   \
                            for (int i = 0; i < 4; ++i) {                       \
                                u16x2 sp  = __builtin_bit_cast(u16x2, sv[i]);   \
                                u16x2 d   = sp - rowdup[T];                     \
                                u16x2 mn  = __builtin_elementwise_min(d, one2); \
                                u16x2 f   = mn * negb + posb;                   \
                                fr[i] = __builtin_bit_cast(unsigned, f);        \
                            }                                                   \
                            if constexpr (MODE == 1) { KEEPV(fr); }             \
                            else {                                              \
                                s16x8 afrag = __builtin_bit_cast(s16x8, fr);    \
                                ACC = __builtin_amdgcn_mfma_f32_16x16x32_bf16(afrag, bfrag, ACC, 0, 0, 0); \
                            }                                                   \
                        }
                        DO_TILE(0, acc0)
                        DO_TILE(1, acc1)
                        DO_TILE(2, acc2)
                        DO_TILE(3, acc3)
#undef DO_TILE
                    }
                }
            }

            cx0 = nx0; cx1 = nx1; cx2 = nx2; cx3 = nx3; csg = nsg;
        }
    }
#undef LOAD_ROUND

    if constexpr (MODE == 2) {
        // aliasing readback: keeps the (otherwise dead) staging stores alive
        float keep = *(const float*)(lds + wbase + (lane & 7) * PLANE + quad * 16);
        KEEP1(keep);
    }

    // ---- cross-wave reduce + global atomics (aliases staging LDS) ----
    __syncthreads();
    float* cl = (float*)lds;
    {
        const int base = ((wid * 4) * 64 + lane) * 4;
        *(f32x4*)(cl + base)            = acc0;
        *(f32x4*)(cl + base + 64 * 4)   = acc1;
        *(f32x4*)(cl + base + 128 * 4)  = acc2;
        *(f32x4*)(cl + base + 192 * 4)  = acc3;
    }
    __syncthreads();

    for (int i = tid; i < SEGS * VALS; i += 256) {
        const int row = i / VALS;
        const int cc  = i - row * VALS;
        const int t   = row >> 4;
        const int rr  = row & 15;
        const int g   = rr >> 2;
        const int reg = rr & 3;
        const int lhi = g * 16 + cc;
        const int llo = lhi + 8;
        float v = 0.0f;
#pragma unroll
        for (int w = 0; w < 4; ++w) {
            v += cl[((w * 4 + t) * 64 + lhi) * 4 + reg];
            v += cl[((w * 4 + t) * 64 + llo) * 4 + reg];
        }
        unsafeAtomicAdd(accOut + ((size_t)blockIdx.y * SEGS + row) * VALS + cc, v);
    }
}

__global__ __launch_bounds__(256) void vl_finalize(const float* __restrict__ acc,
                                                   float* __restrict__ out)
{
    __shared__ float sum_var[B_];
    __shared__ float num_ids[B_];
    if (threadIdx.x < B_) { sum_var[threadIdx.x] = 0.0f; num_ids[threadIdx.x] = 0.0f; }
    __syncthreads();

    for (int i = threadIdx.x; i < B_ * SEGS; i += 256) {
        const float* a = acc + (size_t)i * VALS;
        const int b = i >> 6;
        const float cnt = a[4];
        if (cnt > 1.0f) {
            const float inv_n = 1.0f / cnt;       // n_safe = cnt (cnt > 0)
            const float denom = cnt - 1.0f;       // cnt > 1
            const float s0 = a[0], s1 = a[1], s2 = a[2];
            const float s3 = cnt - s0 - s1 - s2;  // p's sum to 1 per pixel
            const float ssum2 = s0*s0 + s1*s1 + s2*s2 + s3*s3;
            const float sv = (a[3] - ssum2 * inv_n) / denom;
            atomicAdd(&sum_var[b], sv);
        }
        if (cnt > 0.0f) atomicAdd(&num_ids[b], 1.0f);
    }
    __syncthreads();

    if (threadIdx.x == 0) {
        float loss = 0.0f;
#pragma unroll
        for (int b = 0; b < B_; ++b) loss += sum_var[b] / (num_ids[b] + EPS_);
        out[0] = loss / (float)B_;
    }
}

extern "C" void kernel_launch(void* const* d_in, const int* in_sizes, int n_in,
                              void* d_out, int out_size, void* d_ws, size_t ws_size,
                              hipStream_t stream) {
    const float* logit = (const float*)d_in[0];
    const int*   inst  = (const int*)d_in[1];
    float* out = (float*)d_out;
    float* acc = (float*)d_ws;                      // B_*SEGS*VALS f32 = 10240 B

    const int totalPix = in_sizes[1];               // B*H*W
    const int N = totalPix / B_;                    // H*W per batch

    const size_t ACCW = (size_t)B_ * SEGS * VALS;   // floats
    hipMemsetAsync(acc, 0, ACCW * sizeof(float), stream);

    const int gridx = 128;                          // 1024 blocks = 4/CU, 1 gen
    int ppb = (N + gridx - 1) / gridx;
    ppb = (ppb + 1023) & ~1023;

    dim3 grid(gridx, B_);
    vl_accum<0, 1><<<grid, 256, 0, stream>>>(logit, inst, acc, N, ppb);
    vl_finalize<<<1, 256, 0, stream>>>(acc, out);

    // ---- ablation dispatches (dead scratch, never read) ----
    if (ws_size >= 2 * ACCW * sizeof(float)) {
        float* junk = acc + ACCW;
        vl_accum<1, 2><<<grid, 256, 0, stream>>>(logit, inst, junk, N, ppb);
        vl_accum<2, 3><<<grid, 256, 0, stream>>>(logit, inst, junk, N, ppb);
        vl_accum<3, 4><<<grid, 256, 0, stream>>>(logit, inst, junk, N, ppb);
    }
}

// Round 10
// 219.003 us; speedup vs baseline: 2.0776x; 2.0776x over previous
//
#include <hip/hip_runtime.h>

// VarianceLoss via one-hot MFMA segment reduction.  B=8, C=4, H=W=1024, NSEG=65.
//
// R7 ablation: loads+softmax = 24.8us/rep (memory-path roofline), staging
// adds <8us, ds_read+A-build <16us, MFMA step adds >=29us => the 78us is
// serialization (vmcnt at round top after compiler re-sank the prefetch, and
// an 8-deep dependent MFMA chain), not pipe throughput.
//
// R8 restructure (re-run; R9 was an infra failure, container died):
//  - Double-buffered per-wave staging planes: round r's kt/MFMA loop reads
//    the buffer staged in round r-1; softmax+staging of round r+1 runs AFTER
//    the kt loop, so the global-load vmcnt wait hides under ~2500 cyc of
//    MFMA/VALU work.  sched_barrier(0) after load-issue stops the compiler
//    from re-sinking the loads (it did so in R4/R5/R6/R7: VGPR 36-44).
//  - Accumulators split even/odd kt: 8 chains of depth 4 instead of 4 of
//    depth 8 -> halves exposed MFMA dependency latency.  Merged in epilogue.

typedef unsigned short u16x2 __attribute__((ext_vector_type(2)));
typedef unsigned int   u32x4 __attribute__((ext_vector_type(4)));
typedef short          s16x8 __attribute__((ext_vector_type(8)));   // 8 x bf16
typedef float          f32x4 __attribute__((ext_vector_type(4)));

constexpr int   B_    = 8;
constexpr int   SEGS  = 64;      // segments 1..64 (segment 0 masked out by ref)
constexpr int   VALS  = 5;       // p0,p1,p2,qq,cnt
constexpr float EPS_  = 1e-8f;

constexpr int PLANE   = 528;               // bytes per plane (512 + bank skew)
constexpr int NSLOT   = 9;                 // hi0,lo0,hi1,lo1,hi2,lo2,hi3,lo3,seg
constexpr int BUFSZ   = NSLOT * PLANE;     // 4752 B per buffer
constexpr int WLDS    = 2 * BUFSZ;         // 9504 B per wave (double-buffered)
constexpr int LDS_SZ  = (4 * WLDS > 16384) ? 4 * WLDS : 16384;   // 38016

__device__ __forceinline__ unsigned asu(float f)  { return __float_as_uint(f); }
__device__ __forceinline__ float    asf(unsigned u){ return __uint_as_float(u); }

__global__ __launch_bounds__(256, 4) void vl_accum(const float* __restrict__ logit,
                                                   const int*   __restrict__ inst,
                                                   float* __restrict__ accOut,
                                                   int N, int ppb)
{
    __shared__ __align__(16) unsigned char lds[LDS_SZ];

    const int tid  = threadIdx.x;
    const int wid  = tid >> 6;
    const int lane = tid & 63;
    const int col  = lane & 15;
    const int quad = lane >> 4;
    const int wbase = wid * WLDS;

    const bool selLds = (col < 4) | (col >= 8 && col < 12);
    const unsigned cword = (col == 4) ? 0x3F803F80u : 0u;   // cnt hi = 1.0
    const int pl = (col < 4) ? (2 * col)
                 : ((col >= 8 && col < 12) ? (2 * (col - 8) + 1) : 0);
    const int bRd0   = wbase + pl * PLANE + quad * 16;   // + buf*BUFSZ + kt*64
    const int segRd0 = wbase + 8 * PLANE + quad * 16;    // + buf*BUFSZ + kt*64
    const int segWr0 = wbase + 8 * PLANE + lane * 8;     // + buf*BUFSZ

    u16x2 rowdup[4];
#pragma unroll
    for (int t = 0; t < 4; ++t) {
        unsigned short rw = (unsigned short)(t * 16 + col);
        rowdup[t] = (u16x2){rw, rw};
    }
    const u16x2 one2  = (u16x2){1, 1};
    const u16x2 negb  = (u16x2){0xC080, 0xC080};   // -0x3F80 mod 2^16
    const u16x2 posb  = (u16x2){0x3F80, 0x3F80};

    const int b = blockIdx.y;
    const float* __restrict__ l0 = logit + (size_t)b * 4 * N;
    const int*   __restrict__ ib = inst  + (size_t)b * N;

    f32x4 acc0a = {0,0,0,0}, acc1a = {0,0,0,0}, acc2a = {0,0,0,0}, acc3a = {0,0,0,0};
    f32x4 acc0b = {0,0,0,0}, acc1b = {0,0,0,0}, acc2b = {0,0,0,0}, acc3b = {0,0,0,0};

    const int blockStart = blockIdx.x * ppb;
    const int rounds = ppb >> 10;
    const int base0  = blockStart + (wid << 8) + (lane << 2);

#define LOAD_ROUND(R, X0, X1, X2, X3, SG)                                       \
    {                                                                           \
        const int q  = base0 + ((R) << 10);                                     \
        const bool ok = (q + 4 <= N);                                           \
        const int qc = ok ? q : 0;                                              \
        X0 = *(const float4*)(l0 + qc);                                         \
        X1 = *(const float4*)(l0 + (size_t)N     + qc);                         \
        X2 = *(const float4*)(l0 + (size_t)2 * N + qc);                         \
        X3 = *(const float4*)(l0 + (size_t)3 * N + qc);                         \
        int4 sgt = *(const int4*)(ib + qc);                                     \
        SG = ok ? sgt : make_int4(0, 0, 0, 0);                                  \
    }

#define SOFTMAX4(X0, X1, X2, X3, P0, P1, P2, QQ)                                \
    {                                                                           \
        const float sc0[4] = {X0.x, X0.y, X0.z, X0.w};                          \
        const float sc1[4] = {X1.x, X1.y, X1.z, X1.w};                          \
        const float sc2[4] = {X2.x, X2.y, X2.z, X2.w};                          \
        const float sc3[4] = {X3.x, X3.y, X3.z, X3.w};                          \
        _Pragma("unroll")                                                       \
        for (int i = 0; i < 4; ++i) {                                           \
            float va = sc0[i], vb = sc1[i], vc = sc2[i], vd = sc3[i];           \
            float m  = fmaxf(fmaxf(va, vb), fmaxf(vc, vd));                     \
            float e0 = __expf(va - m);                                          \
            float e1 = __expf(vb - m);                                          \
            float e2 = __expf(vc - m);                                          \
            float e3 = __expf(vd - m);                                          \
            float rr = 1.0f / (e0 + e1 + e2 + e3);                              \
            float q0 = e0 * rr, q1 = e1 * rr, q2 = e2 * rr, q3 = e3 * rr;       \
            P0[i] = q0; P1[i] = q1; P2[i] = q2;                                 \
            QQ[i] = q0*q0 + q1*q1 + q2*q2 + q3*q3;                              \
        }                                                                       \
    }

#define STAGE_PLANE(BOFF, P, ARR)                                               \
    {                                                                           \
        unsigned a0 = asu(ARR[0]), a1 = asu(ARR[1]);                            \
        unsigned a2 = asu(ARR[2]), a3 = asu(ARR[3]);                            \
        unsigned h1m = a1 & 0xFFFF0000u, h3m = a3 & 0xFFFF0000u;                \
        unsigned hi01 = (a0 >> 16) | h1m;                                       \
        unsigned hi23 = (a2 >> 16) | h3m;                                       \
        float l0f = ARR[0] - asf(a0 & 0xFFFF0000u);                             \
        float l1f = ARR[1] - asf(h1m);                                          \
        float l2f = ARR[2] - asf(a2 & 0xFFFF0000u);                             \
        float l3f = ARR[3] - asf(h3m);                                          \
        unsigned lo01 = (asu(l0f) >> 16) | (asu(l1f) & 0xFFFF0000u);            \
        unsigned lo23 = (asu(l2f) >> 16) | (asu(l3f) & 0xFFFF0000u);            \
        *(uint2*)(lds + (BOFF) + wbase + (2*(P)) * PLANE + lane * 8)   = make_uint2(hi01, hi23); \
        *(uint2*)(lds + (BOFF) + wbase + (2*(P)+1) * PLANE + lane * 8) = make_uint2(lo01, lo23); \
    }

#define STAGE_ALL(BOFF, P0, P1, P2, QQ, SG)                                     \
    {                                                                           \
        STAGE_PLANE(BOFF, 0, P0)                                                \
        STAGE_PLANE(BOFF, 1, P1)                                                \
        STAGE_PLANE(BOFF, 2, P2)                                                \
        STAGE_PLANE(BOFF, 3, QQ)                                                \
        unsigned r0 = (unsigned)(SG.x - 1) & 0xFFFFu;                           \
        unsigned r1 = (unsigned)(SG.y - 1) & 0xFFFFu;                           \
        unsigned r2 = (unsigned)(SG.z - 1) & 0xFFFFu;                           \
        unsigned r3 = (unsigned)(SG.w - 1) & 0xFFFFu;                           \
        *(uint2*)(lds + (BOFF) + segWr0) = make_uint2(r0 | (r1 << 16), r2 | (r3 << 16)); \
    }

    // ---- prologue: load+softmax+stage round 0 into buffer 0 ----
    if (rounds > 0) {
        float4 cx0, cx1, cx2, cx3; int4 csg;
        LOAD_ROUND(0, cx0, cx1, cx2, cx3, csg)
        float P0[4], P1[4], P2[4], QQ[4];
        SOFTMAX4(cx0, cx1, cx2, cx3, P0, P1, P2, QQ)
        STAGE_ALL(0, P0, P1, P2, QQ, csg)
    }

    for (int r = 0; r < rounds; ++r) {
        // issue next round's global loads FIRST; their vmcnt wait lands after
        // the kt loop (softmax below).  sched_barrier pins the issue point.
        float4 nx0, nx1, nx2, nx3; int4 nsg;
        const bool hasNext = (r + 1 < rounds);
        if (hasNext) LOAD_ROUND(r + 1, nx0, nx1, nx2, nx3, nsg)
        __builtin_amdgcn_sched_barrier(0);

        // ---- kt/MFMA loop on the buffer staged LAST round ----
        const int bufOff = (r & 1) * BUFSZ;
#pragma unroll
        for (int kt = 0; kt < 8; ++kt) {
            s16x8 braw = *(const s16x8*)(lds + bufOff + bRd0   + kt * 64);
            u32x4 sv   = *(const u32x4*)(lds + bufOff + segRd0 + kt * 64);
            u32x4 bw   = __builtin_bit_cast(u32x4, braw);
#pragma unroll
            for (int i = 0; i < 4; ++i) bw[i] = selLds ? bw[i] : cword;
            s16x8 bfrag = __builtin_bit_cast(s16x8, bw);

#define DO_TILE(T, ACC)                                                         \
            {                                                                   \
                u32x4 fr;                                                       \
                _Pragma("unroll")                                               \
                for (int i = 0; i < 4; ++i) {                                   \
                    u16x2 sp  = __builtin_bit_cast(u16x2, sv[i]);               \
                    u16x2 d   = sp - rowdup[T];                                 \
                    u16x2 mn  = __builtin_elementwise_min(d, one2);             \
                    u16x2 f   = mn * negb + posb;  /* 0x3F80 or 0 */            \
                    fr[i] = __builtin_bit_cast(unsigned, f);                    \
                }                                                               \
                s16x8 afrag = __builtin_bit_cast(s16x8, fr);                    \
                ACC = __builtin_amdgcn_mfma_f32_16x16x32_bf16(afrag, bfrag, ACC, 0, 0, 0); \
            }
            if ((kt & 1) == 0) {
                DO_TILE(0, acc0a) DO_TILE(1, acc1a) DO_TILE(2, acc2a) DO_TILE(3, acc3a)
            } else {
                DO_TILE(0, acc0b) DO_TILE(1, acc1b) DO_TILE(2, acc2b) DO_TILE(3, acc3b)
            }
#undef DO_TILE
        }

        // ---- softmax + stage round r+1 into the other buffer ----
        if (hasNext) {
            float P0[4], P1[4], P2[4], QQ[4];
            SOFTMAX4(nx0, nx1, nx2, nx3, P0, P1, P2, QQ)
            const int nOff = ((r + 1) & 1) * BUFSZ;
            STAGE_ALL(nOff, P0, P1, P2, QQ, nsg)
        }
    }
#undef LOAD_ROUND
#undef SOFTMAX4
#undef STAGE_PLANE
#undef STAGE_ALL

    // merge even/odd-kt accumulator halves
    f32x4 acc0 = acc0a + acc0b;
    f32x4 acc1 = acc1a + acc1b;
    f32x4 acc2 = acc2a + acc2b;
    f32x4 acc3 = acc3a + acc3b;

    // ---- cross-wave reduce + global atomics (aliases staging LDS) ----
    __syncthreads();
    float* cl = (float*)lds;               // [w][t][lane][reg] f32 = 16 KB
    {
        const int base = ((wid * 4) * 64 + lane) * 4;
        *(f32x4*)(cl + base)            = acc0;
        *(f32x4*)(cl + base + 64 * 4)   = acc1;
        *(f32x4*)(cl + base + 128 * 4)  = acc2;
        *(f32x4*)(cl + base + 192 * 4)  = acc3;
    }
    __syncthreads();

    for (int i = tid; i < SEGS * VALS; i += 256) {
        const int row = i / VALS;          // 0..63  (= seg-1)
        const int cc  = i - row * VALS;    // 0..4
        const int t   = row >> 4;
        const int rr  = row & 15;
        const int g   = rr >> 2;
        const int reg = rr & 3;
        const int lhi = g * 16 + cc;
        const int llo = lhi + 8;
        float v = 0.0f;
#pragma unroll
        for (int w = 0; w < 4; ++w) {
            v += cl[((w * 4 + t) * 64 + lhi) * 4 + reg];
            v += cl[((w * 4 + t) * 64 + llo) * 4 + reg];
        }
        unsafeAtomicAdd(accOut + ((size_t)blockIdx.y * SEGS + row) * VALS + cc, v);
    }
}

__global__ __launch_bounds__(256) void vl_finalize(const float* __restrict__ acc,
                                                   float* __restrict__ out)
{
    __shared__ float sum_var[B_];
    __shared__ float num_ids[B_];
    if (threadIdx.x < B_) { sum_var[threadIdx.x] = 0.0f; num_ids[threadIdx.x] = 0.0f; }
    __syncthreads();

    for (int i = threadIdx.x; i < B_ * SEGS; i += 256) {
        const float* a = acc + (size_t)i * VALS;
        const int b = i >> 6;
        const float cnt = a[4];
        if (cnt > 1.0f) {
            const float inv_n = 1.0f / cnt;       // n_safe = cnt (cnt > 0)
            const float denom = cnt - 1.0f;       // cnt > 1
            const float s0 = a[0], s1 = a[1], s2 = a[2];
            const float s3 = cnt - s0 - s1 - s2;  // p's sum to 1 per pixel
            const float ssum2 = s0*s0 + s1*s1 + s2*s2 + s3*s3;
            const float sv = (a[3] - ssum2 * inv_n) / denom;
            atomicAdd(&sum_var[b], sv);
        }
        if (cnt > 0.0f) atomicAdd(&num_ids[b], 1.0f);
    }
    __syncthreads();

    if (threadIdx.x == 0) {
        float loss = 0.0f;
#pragma unroll
        for (int b = 0; b < B_; ++b) loss += sum_var[b] / (num_ids[b] + EPS_);
        out[0] = loss / (float)B_;
    }
}

extern "C" void kernel_launch(void* const* d_in, const int* in_sizes, int n_in,
                              void* d_out, int out_size, void* d_ws, size_t ws_size,
                              hipStream_t stream) {
    const float* logit = (const float*)d_in[0];
    const int*   inst  = (const int*)d_in[1];
    float* out = (float*)d_out;
    float* acc = (float*)d_ws;                      // B_*SEGS*VALS f32 = 10240 B

    const int totalPix = in_sizes[1];               // B*H*W
    const int N = totalPix / B_;                    // H*W per batch

    hipMemsetAsync(acc, 0, (size_t)B_ * SEGS * VALS * sizeof(float), stream);

    const int gridx = 128;                          // 1024 blocks = 4/CU (38KB LDS)
    int ppb = (N + gridx - 1) / gridx;
    ppb = (ppb + 1023) & ~1023;                     // 1024-px block rounds

    dim3 grid(gridx, B_);
    vl_accum<<<grid, 256, 0, stream>>>(logit, inst, acc, N, ppb);
    vl_finalize<<<1, 256, 0, stream>>>(acc, out);
}